// Round 9
// baseline (360.245 us; speedup 1.0000x reference)
//
#include <hip/hip_runtime.h>
#include <hip/hip_fp16.h>

#define B_SZ  256
#define IC    1152
#define ID    8
#define OC    10
#define ROWH  160      // halves per (b,i) row of u_hat
#define CH    20       // uint4 (8-half) chunks per row

// ---------------------------------------------------------------------------
// K1: u_hat[i][b][od] = sum_k W[i][od][k] * u[b][i][k], fp16, [i][b] layout.
// grid = 1152 (block = i), 256 threads (thread = b).
// W[i] (5 KB) in LDS, uniform-broadcast reads. Row computed fully into
// registers (20 uint4), then stored as one batched burst of 20 consecutive
// dwordx4 -> every 64B line fully dirtied immediately (kills the 1.55x
// write amplification measured in R6). Block writes one contiguous 80 KB.
// ---------------------------------------------------------------------------
__global__ __launch_bounds__(256) void uhat_ib_kernel(
    const float* __restrict__ u, const float* __restrict__ W,
    uint4* __restrict__ uhat)
{
    const int i = blockIdx.x;
    const int b = threadIdx.x;

    __shared__ float4 Wl[ROWH * 2];   // 1280 f32 = 320 float4 = 5 KB

    const float4* wsrc = (const float4*)(W + (size_t)i * ROWH * ID);
    for (int idx = b; idx < ROWH * 2; idx += 256) Wl[idx] = wsrc[idx];

    const float4* up = (const float4*)(u + ((size_t)b * IC + i) * ID);
    float4 u0 = up[0], u1 = up[1];
    __syncthreads();

    uint4 ro[CH];
    #pragma unroll
    for (int c4 = 0; c4 < CH; ++c4) {
        float o[8];
        #pragma unroll
        for (int j = 0; j < 8; ++j) {
            float4 wa = Wl[(c4 * 8 + j) * 2];
            float4 wb = Wl[(c4 * 8 + j) * 2 + 1];
            o[j] = wa.x * u0.x + wa.y * u0.y + wa.z * u0.z + wa.w * u0.w
                 + wb.x * u1.x + wb.y * u1.y + wb.z * u1.z + wb.w * u1.w;
        }
        union { __half2 h2[4]; uint4 q; } pk;
        pk.h2[0] = __floats2half2_rn(o[0], o[1]);
        pk.h2[1] = __floats2half2_rn(o[2], o[3]);
        pk.h2[2] = __floats2half2_rn(o[4], o[5]);
        pk.h2[3] = __floats2half2_rn(o[6], o[7]);
        ro[c4] = pk.q;
    }

    uint4* dst = uhat + ((size_t)i * B_SZ + b) * CH;
    #pragma unroll
    for (int c4 = 0; c4 < CH; ++c4) dst[c4] = ro[c4];
}

// ---------------------------------------------------------------------------
// K2: all 3 routing passes. One block per b, 1024 threads = 16 waves.
// Lane = ii*16 + os (ii: which of 4 i's per step; os: o-slot, 10 active).
// Each lane holds the full 32B u_hat row for its (i,o): in-lane 16-d dot,
// one exp per (i,o) (pass 0 exp-free uniform c), Z via 4 shfls, s[16] regs.
// Depth-4 load pipeline (4 outstanding 32B loads/lane), fully unrolled so
// the P[4][2] rotation stays in registers (no scratch).
// u_hat layout [i][b]: row (i,b) at ((i*256)+b)*320 bytes.
// ---------------------------------------------------------------------------
__global__ __launch_bounds__(1024) void routing3_kernel(
    const uint4* __restrict__ uhat, float* __restrict__ out)
{
    const int b  = blockIdx.x;
    const int t  = threadIdx.x;
    const int wv = t >> 6;
    const int ln = t & 63;
    const int ii = ln >> 4;
    const int os = ln & 15;
    const bool act = (os < OC);
    const int o  = act ? os : (OC - 1);

    __shared__ float sred[16][164];   // +4 pad
    __shared__ float vl[ROWH];

    // step it: i = wv*72 + it*4 + ii
    const char* base = (const char*)uhat
                     + ((size_t)(wv * 72 + ii) * B_SZ + b) * 320 + o * 32;
    const size_t STEP = (size_t)4 * B_SZ * 320;   // 327,680 B per it-step

    float v[16];
    #pragma unroll
    for (int j = 0; j < 16; ++j) v[j] = 0.f;

    for (int p = 0; p < 3; ++p) {
        float s[16];
        #pragma unroll
        for (int j = 0; j < 16; ++j) s[j] = 0.f;

        uint4 P[4][2];
        #pragma unroll
        for (int k = 0; k < 4; ++k) {
            const char* ap = base + (size_t)k * STEP;
            P[k][0] = *(const uint4*)ap;
            P[k][1] = *(const uint4*)(ap + 16);
        }

        #pragma unroll
        for (int it = 0; it < 18; ++it) {
            const int slot = it & 3;          // constant under full unroll
            uint4 A0 = P[slot][0];
            uint4 A1 = P[slot][1];
            if (it + 4 < 18) {
                const char* np = base + (size_t)(it + 4) * STEP;
                P[slot][0] = *(const uint4*)np;
                P[slot][1] = *(const uint4*)(np + 16);
            }

            float r[16];
            const __half2* hp0 = (const __half2*)&A0;
            const __half2* hp1 = (const __half2*)&A1;
            #pragma unroll
            for (int q = 0; q < 4; ++q) {
                float2 f = __half22float2(hp0[q]);
                float2 g = __half22float2(hp1[q]);
                r[2 * q]     = f.x; r[2 * q + 1] = f.y;
                r[8 + 2 * q] = g.x; r[9 + 2 * q] = g.y;
            }

            if (p == 0) {
                #pragma unroll
                for (int j = 0; j < 16; ++j) s[j] += r[j];   // c uniform; 0.1 later
            } else {
                float a = 0.f;
                #pragma unroll
                for (int j = 0; j < 16; ++j) a += r[j] * v[j];

                float e = act ? __expf(a) : 0.f;
                float Z = e;
                Z += __shfl_xor(Z, 1);
                Z += __shfl_xor(Z, 2);
                Z += __shfl_xor(Z, 4);
                Z += __shfl_xor(Z, 8);
                float cf = __fdividef(e, Z);

                #pragma unroll
                for (int j = 0; j < 16; ++j) s[j] += cf * r[j];
            }
        }

        // reduce over the 4 ii (lanes xor 16, 32 share the same os)
        #pragma unroll
        for (int j = 0; j < 16; ++j) {
            s[j] += __shfl_xor(s[j], 16);
            s[j] += __shfl_xor(s[j], 32);
        }
        if (ln < 16 && act) {   // ii==0, os<10: wave-total for o=os
            float4* dst = (float4*)&sred[wv][os * 16];
            dst[0] = make_float4(s[0],  s[1],  s[2],  s[3]);
            dst[1] = make_float4(s[4],  s[5],  s[6],  s[7]);
            dst[2] = make_float4(s[8],  s[9],  s[10], s[11]);
            dst[3] = make_float4(s[12], s[13], s[14], s[15]);
        }
        __syncthreads();

        if (t < ROWH) {
            float S = 0.f;
            #pragma unroll
            for (int w2 = 0; w2 < 16; ++w2) S += sred[w2][t];
            if (p == 0) S *= 0.1f;
            float n2 = S * S;
            n2 += __shfl_xor(n2, 1);
            n2 += __shfl_xor(n2, 2);
            n2 += __shfl_xor(n2, 4);
            n2 += __shfl_xor(n2, 8);
            float sc = (n2 / (1.0f + n2)) * rsqrtf(n2 + 1e-8f);
            vl[t] = S * sc;
        }
        __syncthreads();

        if (p < 2) {   // v <- v0 (p0) ; v <- v0+v1 (p1)
            const float4* vp = (const float4*)&vl[o * 16];
            float4 q0 = vp[0], q1 = vp[1], q2 = vp[2], q3 = vp[3];
            if (p == 0) {
                v[0]=q0.x; v[1]=q0.y; v[2]=q0.z; v[3]=q0.w;
                v[4]=q1.x; v[5]=q1.y; v[6]=q1.z; v[7]=q1.w;
                v[8]=q2.x; v[9]=q2.y; v[10]=q2.z; v[11]=q2.w;
                v[12]=q3.x; v[13]=q3.y; v[14]=q3.z; v[15]=q3.w;
            } else {
                v[0]+=q0.x; v[1]+=q0.y; v[2]+=q0.z; v[3]+=q0.w;
                v[4]+=q1.x; v[5]+=q1.y; v[6]+=q1.z; v[7]+=q1.w;
                v[8]+=q2.x; v[9]+=q2.y; v[10]+=q2.z; v[11]+=q2.w;
                v[12]+=q3.x; v[13]+=q3.y; v[14]+=q3.z; v[15]+=q3.w;
            }
            __syncthreads();   // protect sred/vl before next pass rewrites them
        }
    }

    if (t < 2 * CH) {
        ((float4*)out)[(size_t)b * 2 * CH + t] = ((const float4*)vl)[t];
    }
}

// ---------------------------------------------------------------------------
extern "C" void kernel_launch(void* const* d_in, const int* in_sizes, int n_in,
                              void* d_out, int out_size, void* d_ws, size_t ws_size,
                              hipStream_t stream)
{
    const float* u = (const float*)d_in[0];
    const float* W = (const float*)d_in[1];

    uint4* uhat = (uint4*)d_ws;   // 1152*256*320 B = 94.4 MB, [i][b] layout

    uhat_ib_kernel<<<IC, 256, 0, stream>>>(u, W, uhat);
    routing3_kernel<<<B_SZ, 1024, 0, stream>>>(uhat, (float*)d_out);
}

// Round 11
// 150.095 us; speedup vs baseline: 2.4001x; 2.4001x over previous
//
#include <hip/hip_runtime.h>
#include <hip/hip_fp16.h>

#define B_SZ  256
#define IC    1152
#define ID    8
#define OC    10
#define ROWH  160      // halves per (b,i) row of u_hat
#define CH    20       // uint4 (8-half) chunks per row

// ---------------------------------------------------------------------------
// K1: u_hat[i][b][od] = sum_k W[i][od][k] * u[b][i][k], fp16, [i][b] layout.
// grid = 1152 (block = i), 256 threads (thread = b).
// W[i] (5 KB) in LDS, uniform-broadcast reads. Row computed fully into
// registers (20 uint4), then stored as one batched burst of 20 consecutive
// dwordx4 -> every 64B line fully dirtied immediately (targets the 1.55x
// write amplification measured in R6). Block writes one contiguous 80 KB.
// ---------------------------------------------------------------------------
__global__ __launch_bounds__(256) void uhat_ib_kernel(
    const float* __restrict__ u, const float* __restrict__ W,
    uint4* __restrict__ uhat)
{
    const int i = blockIdx.x;
    const int b = threadIdx.x;

    __shared__ float4 Wl[ROWH * 2];   // 1280 f32 = 320 float4 = 5 KB

    const float4* wsrc = (const float4*)(W + (size_t)i * ROWH * ID);
    for (int idx = b; idx < ROWH * 2; idx += 256) Wl[idx] = wsrc[idx];

    const float4* up = (const float4*)(u + ((size_t)b * IC + i) * ID);
    float4 u0 = up[0], u1 = up[1];
    __syncthreads();

    uint4 ro[CH];
    #pragma unroll
    for (int c4 = 0; c4 < CH; ++c4) {
        float o[8];
        #pragma unroll
        for (int j = 0; j < 8; ++j) {
            float4 wa = Wl[(c4 * 8 + j) * 2];
            float4 wb = Wl[(c4 * 8 + j) * 2 + 1];
            o[j] = wa.x * u0.x + wa.y * u0.y + wa.z * u0.z + wa.w * u0.w
                 + wb.x * u1.x + wb.y * u1.y + wb.z * u1.z + wb.w * u1.w;
        }
        union { __half2 h2[4]; uint4 q; } pk;
        pk.h2[0] = __floats2half2_rn(o[0], o[1]);
        pk.h2[1] = __floats2half2_rn(o[2], o[3]);
        pk.h2[2] = __floats2half2_rn(o[4], o[5]);
        pk.h2[3] = __floats2half2_rn(o[6], o[7]);
        ro[c4] = pk.q;
    }

    uint4* dst = uhat + ((size_t)i * B_SZ + b) * CH;
    #pragma unroll
    for (int c4 = 0; c4 < CH; ++c4) dst[c4] = ro[c4];
}

// ---------------------------------------------------------------------------
// K2: all 3 routing passes. One block per b, 1024 threads = 16 waves.
// Lane = ii*16 + os (ii: which of 4 i's per step; os: o-slot, 10 active).
// Each lane holds the full 32B u_hat row for its (i,o): in-lane 16-d dot,
// one exp per (i,o) (pass 0 exp-free uniform c), Z via 4 shfls, s[16] regs.
// Depth-2 pipeline with NAMED registers A0/A1/B0/B1 (R6-proven, no runtime
// array indexing -> no scratch spill; cf. R9 post-mortem: P[4][2] spilled
// 254 MB). __launch_bounds__(1024, 4): 4 waves/SIMD -> VGPR cap 128.
// u_hat layout [i][b]: row (i,b) at ((i*256)+b)*320 bytes.
// ---------------------------------------------------------------------------
__global__ __launch_bounds__(1024, 4) void routing3_kernel(
    const uint4* __restrict__ uhat, float* __restrict__ out)
{
    const int b  = blockIdx.x;
    const int t  = threadIdx.x;
    const int wv = t >> 6;
    const int ln = t & 63;
    const int ii = ln >> 4;
    const int os = ln & 15;
    const bool act = (os < OC);
    const int o  = act ? os : (OC - 1);

    __shared__ float sred[16][164];   // +4 pad
    __shared__ float vl[ROWH];

    // step it: i = wv*72 + it*4 + ii
    const char* base = (const char*)uhat
                     + ((size_t)(wv * 72 + ii) * B_SZ + b) * 320 + o * 32;
    const size_t STEP = (size_t)4 * B_SZ * 320;   // advance 4 i per step

    float v[16];
    #pragma unroll
    for (int j = 0; j < 16; ++j) v[j] = 0.f;

    for (int p = 0; p < 3; ++p) {
        float s[16];
        #pragma unroll
        for (int j = 0; j < 16; ++j) s[j] = 0.f;

        uint4 A0 = *(const uint4*)(base);
        uint4 A1 = *(const uint4*)(base + 16);
        uint4 B0 = *(const uint4*)(base + STEP);
        uint4 B1 = *(const uint4*)(base + STEP + 16);

        #pragma unroll 2
        for (int it = 0; it < 18; ++it) {
            uint4 N0 = B0, N1 = B1;
            if (it + 2 < 18) {
                const char* np = base + (size_t)(it + 2) * STEP;
                N0 = *(const uint4*)np;
                N1 = *(const uint4*)(np + 16);
            }

            float r[16];
            const __half2* hp0 = (const __half2*)&A0;
            const __half2* hp1 = (const __half2*)&A1;
            #pragma unroll
            for (int q = 0; q < 4; ++q) {
                float2 f = __half22float2(hp0[q]);
                float2 g = __half22float2(hp1[q]);
                r[2 * q]     = f.x; r[2 * q + 1] = f.y;
                r[8 + 2 * q] = g.x; r[9 + 2 * q] = g.y;
            }

            if (p == 0) {
                #pragma unroll
                for (int j = 0; j < 16; ++j) s[j] += r[j];   // c uniform; 0.1 later
            } else {
                float a = 0.f;
                #pragma unroll
                for (int j = 0; j < 16; ++j) a += r[j] * v[j];

                float e = act ? __expf(a) : 0.f;
                float Z = e;
                Z += __shfl_xor(Z, 1);
                Z += __shfl_xor(Z, 2);
                Z += __shfl_xor(Z, 4);
                Z += __shfl_xor(Z, 8);
                float cf = __fdividef(e, Z);

                #pragma unroll
                for (int j = 0; j < 16; ++j) s[j] += cf * r[j];
            }

            A0 = B0; A1 = B1; B0 = N0; B1 = N1;
        }

        // reduce over the 4 ii (lanes xor 16, 32 share the same os)
        #pragma unroll
        for (int j = 0; j < 16; ++j) {
            s[j] += __shfl_xor(s[j], 16);
            s[j] += __shfl_xor(s[j], 32);
        }
        if (ln < 16 && act) {   // ii==0, os<10: wave-total for o=os
            float4* dst = (float4*)&sred[wv][os * 16];
            dst[0] = make_float4(s[0],  s[1],  s[2],  s[3]);
            dst[1] = make_float4(s[4],  s[5],  s[6],  s[7]);
            dst[2] = make_float4(s[8],  s[9],  s[10], s[11]);
            dst[3] = make_float4(s[12], s[13], s[14], s[15]);
        }
        __syncthreads();

        if (t < ROWH) {
            float S = 0.f;
            #pragma unroll
            for (int w2 = 0; w2 < 16; ++w2) S += sred[w2][t];
            if (p == 0) S *= 0.1f;
            float n2 = S * S;
            n2 += __shfl_xor(n2, 1);
            n2 += __shfl_xor(n2, 2);
            n2 += __shfl_xor(n2, 4);
            n2 += __shfl_xor(n2, 8);
            float sc = (n2 / (1.0f + n2)) * rsqrtf(n2 + 1e-8f);
            vl[t] = S * sc;
        }
        __syncthreads();

        if (p < 2) {   // v <- v0 (p0) ; v <- v0+v1 (p1)
            const float4* vp = (const float4*)&vl[o * 16];
            float4 q0 = vp[0], q1 = vp[1], q2 = vp[2], q3 = vp[3];
            if (p == 0) {
                v[0]=q0.x; v[1]=q0.y; v[2]=q0.z; v[3]=q0.w;
                v[4]=q1.x; v[5]=q1.y; v[6]=q1.z; v[7]=q1.w;
                v[8]=q2.x; v[9]=q2.y; v[10]=q2.z; v[11]=q2.w;
                v[12]=q3.x; v[13]=q3.y; v[14]=q3.z; v[15]=q3.w;
            } else {
                v[0]+=q0.x; v[1]+=q0.y; v[2]+=q0.z; v[3]+=q0.w;
                v[4]+=q1.x; v[5]+=q1.y; v[6]+=q1.z; v[7]+=q1.w;
                v[8]+=q2.x; v[9]+=q2.y; v[10]+=q2.z; v[11]+=q2.w;
                v[12]+=q3.x; v[13]+=q3.y; v[14]+=q3.z; v[15]+=q3.w;
            }
            __syncthreads();   // protect sred/vl before next pass rewrites them
        }
    }

    if (t < 2 * CH) {
        ((float4*)out)[(size_t)b * 2 * CH + t] = ((const float4*)vl)[t];
    }
}

// ---------------------------------------------------------------------------
extern "C" void kernel_launch(void* const* d_in, const int* in_sizes, int n_in,
                              void* d_out, int out_size, void* d_ws, size_t ws_size,
                              hipStream_t stream)
{
    const float* u = (const float*)d_in[0];
    const float* W = (const float*)d_in[1];

    uint4* uhat = (uint4*)d_ws;   // 1152*256*320 B = 94.4 MB, [i][b] layout

    uhat_ib_kernel<<<IC, 256, 0, stream>>>(u, W, uhat);
    routing3_kernel<<<B_SZ, 1024, 0, stream>>>(uhat, (float*)d_out);
}